// Round 20
// baseline (878.501 us; speedup 1.0000x reference)
//
#include <hip/hip_runtime.h>
#include <cstdint>

#define DEV static __device__ __forceinline__

typedef __attribute__((ext_vector_type(4))) float f32x4;
typedef __attribute__((ext_vector_type(4))) float fl4;
typedef __attribute__((ext_vector_type(4))) unsigned short us4;
typedef __attribute__((ext_vector_type(8))) unsigned short us8;
typedef __attribute__((ext_vector_type(2))) long l2v;          // 2 x i64 (one b128)

DEV float b2f(unsigned short u) {
  union { unsigned int i; float f; } c; c.i = ((unsigned int)u) << 16; return c.f;
}
DEV unsigned short f2b(float f) {   // RNE float -> bf16 bits
  union { float f; unsigned int i; } c; c.f = f;
  unsigned int u = c.i;
  u += 0x7fffu + ((u >> 16) & 1u);
  return (unsigned short)(u >> 16);
}
DEV unsigned int f4_to_fp8x4(float a, float b, float c, float d) {  // 4 x e4m3 packed
  int r = __builtin_amdgcn_cvt_pk_fp8_f32(a, b, 0, false);
  r = __builtin_amdgcn_cvt_pk_fp8_f32(c, d, r, true);
  return (unsigned int)r;
}
DEV unsigned char f2f8(float v) {   // scalar e4m3
  return (unsigned char)__builtin_amdgcn_cvt_pk_fp8_f32(v, v, 0, false);
}

DEV void gload16(const void* g, void* l) {  // async global->LDS, 16B/lane
  __builtin_amdgcn_global_load_lds(
      (const __attribute__((address_space(1))) unsigned int*)g,
      (__attribute__((address_space(3))) unsigned int*)l, 16, 0, 0);
}

DEV float red16(float v) {  // reduce across 16 lanes sharing lk (xor low 4 bits)
  v += __shfl_xor(v, 1); v += __shfl_xor(v, 2);
  v += __shfl_xor(v, 4); v += __shfl_xor(v, 8);
  return v;
}
DEV float red4lk(float v) { // reduce across the 4 lk groups (xor bits 4,5)
  v += __shfl_xor(v, 16); v += __shfl_xor(v, 32);
  return v;
}

// ---------------- x -> bf16 (residual) + fp8 (GEMM A operand) ----------------
__global__ __launch_bounds__(256) void k_xcast(const float* __restrict__ src,
                                               unsigned short* __restrict__ dh,
                                               unsigned char* __restrict__ d8, long n) {
  long i = ((long)blockIdx.x * 256 + threadIdx.x) * 4;
  if (i >= n) return;
  fl4 v = *(const fl4*)(src + i);
  us4 o;
  o[0] = f2b(v[0]); o[1] = f2b(v[1]); o[2] = f2b(v[2]); o[3] = f2b(v[3]);
  *(us4*)(dh + i) = o;
  *(unsigned int*)(d8 + i) = f4_to_fp8x4(v[0], v[1], v[2], v[3]);
}

// ---------------- Wq|Wk|Wv -> one contiguous fp8 buffer ----------------
__global__ __launch_bounds__(256) void k_wcast8(const float* __restrict__ wq,
                                                const float* __restrict__ wk,
                                                const float* __restrict__ wv,
                                                unsigned char* __restrict__ dst) {
  const long i = ((long)blockIdx.x * 256 + threadIdx.x) * 4;   // [0, 3M)
  const int seg = (int)(i >> 20);
  const float* s = seg == 0 ? wq : (seg == 1 ? wk : wv);
  fl4 v = *(const fl4*)(s + (i & 1048575));
  *(unsigned int*)(dst + i) = f4_to_fp8x4(v[0], v[1], v[2], v[3]);
}

// ---------------- concat biases into 3072-float buffer ----------------
__global__ __launch_bounds__(256) void k_bias_cat(const float* __restrict__ bq,
                                                  const float* __restrict__ bk,
                                                  const float* __restrict__ bv,
                                                  float* __restrict__ o) {
  const int t = blockIdx.x * 256 + threadIdx.x;   // 3072
  o[t] = t < 1024 ? bq[t] : (t < 2048 ? bk[t - 1024] : bv[t - 2048]);
}

#define MFMA_FP8(A, B, C) __builtin_amdgcn_mfma_f32_16x16x32_fp8_fp8((A), (B), (C), 0, 0, 0)
#define SBAR   __builtin_amdgcn_s_barrier()

// Shared K-loop pattern (all 3 GEMMs): 16 waves (4x4 of 64x64), BK=64 fp8, 4 LDS bufs,
// stage t+2, counted vmcnt, barrier every 2nd tile, and NEW: one-tile-ahead register
// frag prefetch (static Ac/Bc <-> An/Bn ping-pong; reads of tile t+1 are issued before
// tile t's MFMA cluster so each wave self-overlaps LDS latency with MFMA issue).
// vmcnt induction: outstanding at each QBODY = {stage(t+1), stage(t+2)} -> vmcnt(2)
// drains exactly stage(t+1); tail (no stage issued) uses vmcnt(0).

#define RDFRAGS(T, AF, BF)                                                    \
  {                                                                           \
    const unsigned char* Asc_ = LDSU + ((T) & 3) * 16384;                     \
    const unsigned char* Bsc_ = LDSU + 65536 + ((T) & 3) * 16384;             \
    _Pragma("unroll")                                                         \
    for (int j_ = 0; j_ < 4; ++j_)                                            \
      BF[j_] = *(const l2v*)&Bsc_[bbase + j_ * 1024 + rdsw];                  \
    _Pragma("unroll")                                                         \
    for (int i_ = 0; i_ < 4; ++i_)                                            \
      AF[i_] = *(const l2v*)&Asc_[abase + i_ * 1024 + rdsw];                  \
  }

#define MFMACLUST(AC, BC)                                                     \
  {                                                                           \
    __builtin_amdgcn_s_setprio(1);                                            \
    _Pragma("unroll")                                                         \
    for (int i_ = 0; i_ < 4; ++i_)                                            \
      _Pragma("unroll")                                                       \
      for (int j_ = 0; j_ < 4; ++j_) {                                        \
        acc[i_][j_] = MFMA_FP8(AC[i_][0], BC[j_][0], acc[i_][j_]);            \
        acc[i_][j_] = MFMA_FP8(AC[i_][1], BC[j_][1], acc[i_][j_]);            \
      }                                                                       \
    __builtin_amdgcn_s_setprio(0);                                            \
  }

#define QBODY(T, STG, AC, BC, AN, BN)                                         \
  {                                                                           \
    if ((T) + 2 < NT) {                                                       \
      STG((T) + 2, ((T) + 2) & 3)                                             \
      asm volatile("s_waitcnt vmcnt(2)" ::: "memory");                        \
      RDFRAGS((T) + 1, AN, BN)                                                \
    } else if ((T) + 1 < NT) {                                                \
      asm volatile("s_waitcnt vmcnt(0)" ::: "memory");                        \
      RDFRAGS((T) + 1, AN, BN)                                                \
    }                                                                         \
    MFMACLUST(AC, BC)                                                         \
  }

// ================= 16-WAVE fp8 QKV =====================================================
__global__ __launch_bounds__(1024, 4)
void k_g16qkv8(const unsigned char* __restrict__ A,
               const unsigned char* __restrict__ Bt,
               unsigned char* __restrict__ QT8, unsigned char* __restrict__ KT8,
               unsigned char* __restrict__ Vout8,
               int Kb,
               const float* __restrict__ bias,
               float* __restrict__ r1, float* __restrict__ r2,
               float* __restrict__ r3, float* __restrict__ r4) {
  __shared__ __align__(16) unsigned char LDSU[131072];

  const int tid = threadIdx.x;
  const int wv = tid >> 6, lane = tid & 63;
  const int wr = wv >> 2, wcn = wv & 3;          // 4 x 4 wave grid, 64x64 each
  const int l15 = lane & 15, lk = lane >> 4;

  const int nx = gridDim.x;
  const int nwg = nx * gridDim.y;
  const int lin = blockIdx.y * nx + blockIdx.x;
  const int cpx = nwg >> 3;
  const int wg = (lin & 7) * cpx + (lin >> 3);
  const int bn = wg % nx;
  const int bm = wg / nx;

  const unsigned char* Ab = A + (long)bm * 256 * Kb;
  const unsigned char* Bb = Bt + (long)bn * 256 * Kb;

  const int scsw = (tid & 3) ^ ((tid >> 3) & 3);
  const long gOff = (long)(tid >> 2) * Kb + (long)scsw * 16;   // bytes; + t*64
  const int ldsb = wv * 1024;

  const int rdsw = (lk ^ ((l15 >> 1) & 3)) * 16;
  const int abase = (wr * 64 + l15) * 64;
  const int bbase = (wcn * 64 + l15) * 64;

  f32x4 acc[4][4];
#pragma unroll
  for (int i = 0; i < 4; ++i)
#pragma unroll
    for (int j = 0; j < 4; ++j) acc[i][j] = (f32x4){0.f, 0.f, 0.f, 0.f};

#define STAGEQ(T, BUF)                                                        \
  {                                                                           \
    const long kb = (long)(T) * 64;                                           \
    gload16(Ab + kb + gOff, LDSU + (BUF) * 16384 + ldsb);                     \
    gload16(Bb + kb + gOff, LDSU + 65536 + (BUF) * 16384 + ldsb);             \
  }

  STAGEQ(0, 0)
  STAGEQ(1, 1)
  asm volatile("s_waitcnt vmcnt(2)" ::: "memory");
  SBAR;

  l2v Ac[4], Bc[4], An[4], Bn[4];
  RDFRAGS(0, Ac, Bc)

  const int NT = Kb >> 6;
  for (int t = 0; t < NT; t += 2) {
    SBAR;
    QBODY(t,     STAGEQ, Ac, Bc, An, Bn)
    QBODY(t + 1, STAGEQ, An, Bn, Ac, Bc)
  }
#undef STAGEQ
  SBAR;   // K-loop LDS dead -> scratch

  const int row0 = bm * 256 + wr * 64;
  const int col0 = bn * 256 + wcn * 64;

  const int seg = bn >> 2;             // 0=Q, 1=K, 2=V
  const int b = bm >> 3;               // batch
  float bvj[4];
#pragma unroll
  for (int j = 0; j < 4; ++j) bvj[j] = bias[col0 + j * 16 + l15];
  const int colL0 = col0 & 1023;
  unsigned char* sc8 = LDSU;           // [256][256B] fp8 scratch, 16B cells ^ (row&15)

  if (seg < 2) {
#pragma unroll
    for (int i = 0; i < 4; ++i)
#pragma unroll
      for (int j = 0; j < 4; ++j) {
        const int p = wcn * 64 + j * 16 + l15;
        const int m = wr * 64 + i * 16 + lk * 4;
        const unsigned int pk4 = f4_to_fp8x4(acc[i][j][0] + bvj[j], acc[i][j][1] + bvj[j],
                                             acc[i][j][2] + bvj[j], acc[i][j][3] + bvj[j]);
        *(unsigned int*)&sc8[p * 256 + (((m >> 4) ^ (p & 15)) << 4) + (m & 15)] = pk4;
      }
#pragma unroll
    for (int j = 0; j < 4; ++j) {
      const int colL = colL0 + j * 16 + l15;
      float ss = 0.f, sm = 0.f;
#pragma unroll
      for (int i = 0; i < 4; ++i)
#pragma unroll
        for (int r = 0; r < 4; ++r) {
          const float v = acc[i][j][r] + bvj[j];
          ss += v * v; sm += v;
        }
      ss = red4lk(ss);
      if (seg == 0) sm = red4lk(sm);
      if (lk == 0) {
        atomicAdd(&(seg == 0 ? r1 : r3)[(long)b * 1024 + colL], ss);
        if (seg == 0) atomicAdd(&r2[(long)b * 1024 + colL], sm);
      }
    }
    SBAR;
    unsigned char* tp = (seg == 0 ? QT8 : KT8) + (long)b * 2097152;
    const int P0 = (bn & 3) * 256;
    const int M0 = (bm & 7) * 256;
#pragma unroll
    for (int it = 0; it < 4; ++it) {
      const int p = it * 64 + (tid >> 4);
      const int c = tid & 15;
      us8 v = *(const us8*)&sc8[p * 256 + ((c ^ (p & 15)) << 4)];
      *(us8*)&tp[(long)(P0 + p) * 2048 + M0 + c * 16] = v;
    }
  } else {
#pragma unroll
    for (int i = 0; i < 4; ++i)
#pragma unroll
      for (int r = 0; r < 4; ++r) {
        const int rl = wr * 64 + i * 16 + lk * 4 + r;
        float sm = 0.f;
#pragma unroll
        for (int j = 0; j < 4; ++j) {
          const float v = acc[i][j][r] + bvj[j];
          sm += v;
          const int col = wcn * 64 + j * 16 + l15;
          sc8[rl * 256 + (((col >> 4) ^ (rl & 15)) << 4) + (col & 15)] = f2f8(v);
        }
        sm = red16(sm);
        if (l15 == 0) atomicAdd(&r4[row0 + i * 16 + lk * 4 + r], sm);
      }
    SBAR;
    const int C0 = (bn & 3) * 256;
#pragma unroll
    for (int it = 0; it < 4; ++it) {
      const int rl = it * 64 + (tid >> 4);
      const int c = tid & 15;
      us8 v = *(const us8*)&sc8[rl * 256 + ((c ^ (rl & 15)) << 4)];
      *(us8*)&Vout8[(long)(bm * 256 + rl) * 1024 + C0 + c * 16] = v;
    }
  }
}

// ================= 16-WAVE fp8 S-GEMM (+fused inverse-norm scaling) ====================
__global__ __launch_bounds__(1024, 4)
void k_g16s8(const unsigned char* __restrict__ A,
             const unsigned char* __restrict__ Bt,
             unsigned char* __restrict__ Sout,
             int Kb,
             const float* __restrict__ pq, const float* __restrict__ pk,
             float* __restrict__ Srow) {
  __shared__ __align__(16) unsigned char LDSU[131072];

  const int tid = threadIdx.x;
  const int wv = tid >> 6, lane = tid & 63;
  const int wr = wv >> 2, wcn = wv & 3;
  const int l15 = lane & 15, lk = lane >> 4;

  const int nx = gridDim.x;
  const int nwg = nx * gridDim.y;
  const int lin = blockIdx.y * nx + blockIdx.x;
  const int cpx = nwg >> 3;
  const int wg = (lin & 7) * cpx + (lin >> 3);
  const int bn = wg % nx;
  const int bm = wg / nx;
  const int bz = blockIdx.z;

  const unsigned char* Ab = A + (long)bz * 2097152 + (long)bm * 256 * Kb;
  const unsigned char* Bb = Bt + (long)bz * 2097152 + (long)bn * 256 * Kb;

  const int scsw = (tid & 3) ^ ((tid >> 3) & 3);
  const long gOff = (long)(tid >> 2) * Kb + (long)scsw * 16;
  const int ldsb = wv * 1024;

  const int rdsw = (lk ^ ((l15 >> 1) & 3)) * 16;
  const int abase = (wr * 64 + l15) * 64;
  const int bbase = (wcn * 64 + l15) * 64;

  f32x4 acc[4][4];
#pragma unroll
  for (int i = 0; i < 4; ++i)
#pragma unroll
    for (int j = 0; j < 4; ++j) acc[i][j] = (f32x4){0.f, 0.f, 0.f, 0.f};

#define STAGES(T, BUF)                                                        \
  {                                                                           \
    const long kb = (long)(T) * 64;                                           \
    gload16(Ab + kb + gOff, LDSU + (BUF) * 16384 + ldsb);                     \
    gload16(Bb + kb + gOff, LDSU + 65536 + (BUF) * 16384 + ldsb);             \
  }

  STAGES(0, 0)
  STAGES(1, 1)
  asm volatile("s_waitcnt vmcnt(2)" ::: "memory");
  SBAR;

  l2v Ac[4], Bc[4], An[4], Bn[4];
  RDFRAGS(0, Ac, Bc)

  const int NT = Kb >> 6;
  for (int t = 0; t < NT; t += 2) {
    SBAR;
    QBODY(t,     STAGES, Ac, Bc, An, Bn)
    QBODY(t + 1, STAGES, An, Bn, Ac, Bc)
  }
#undef STAGES
  SBAR;

  const int row0 = bm * 256 + wr * 64;
  const int col0 = bn * 256 + wcn * 64;
  unsigned char* sc8 = LDSU;

  float ivk[4];
#pragma unroll
  for (int j = 0; j < 4; ++j) ivk[j] = rsqrtf(pk[bz * 1024 + col0 + j * 16 + l15]);
#pragma unroll
  for (int i = 0; i < 4; ++i)
#pragma unroll
    for (int r = 0; r < 4; ++r) {
      const int rl = wr * 64 + i * 16 + lk * 4 + r;
      const float ivq = rsqrtf(pq[bz * 1024 + row0 + i * 16 + lk * 4 + r]);
      float sm = 0.f;
#pragma unroll
      for (int j = 0; j < 4; ++j) {
        const float v = acc[i][j][r] * ivq * ivk[j];
        sm += v;
        const int col = wcn * 64 + j * 16 + l15;
        sc8[rl * 256 + (((col >> 4) ^ (rl & 15)) << 4) + (col & 15)] = f2f8(v);
      }
      sm = red16(sm);
      if (l15 == 0) atomicAdd(&Srow[(long)bz * 1024 + row0 + i * 16 + lk * 4 + r], sm);
    }
  SBAR;
  unsigned char* Cb = Sout + (long)bz * 1048576;
#pragma unroll
  for (int it = 0; it < 4; ++it) {
    const int rl = it * 64 + (tid >> 4);
    const int c = tid & 15;
    us8 v = *(const us8*)&sc8[rl * 256 + ((c ^ (rl & 15)) << 4)];
    *(us8*)&Cb[(long)(bm * 256 + rl) * 1024 + bn * 256 + c * 16] = v;
  }
}

// ================= 16-WAVE fp8 final GEMM (+fused tailor) ==============================
__global__ __launch_bounds__(1024, 4)
void k_g16fin(const unsigned char* __restrict__ A,
              const unsigned char* __restrict__ Bt,
              float* __restrict__ Out,
              int Kb,
              const unsigned short* __restrict__ xh,
              const float* __restrict__ Vsum,
              const float* __restrict__ Srow,
              const float* __restrict__ pq,
              const float* __restrict__ qsum,
              const float* __restrict__ gptr) {
  __shared__ __align__(16) unsigned char LDSU[131072];

  const int tid = threadIdx.x;
  const int wv = tid >> 6, lane = tid & 63;
  const int wr = wv >> 2, wcn = wv & 3;
  const int l15 = lane & 15, lk = lane >> 4;

  const int nx = gridDim.x;
  const int nwg = nx * gridDim.y;
  const int lin = blockIdx.y * nx + blockIdx.x;
  const int cpx = nwg >> 3;
  const int wg = (lin & 7) * cpx + (lin >> 3);
  const int bn = wg % nx;
  const int bm = wg / nx;
  const int bz = blockIdx.z;

  const unsigned char* Ab = A + (long)bz * 2097152 + (long)bm * 256 * Kb;
  const unsigned char* Bb = Bt + (long)bz * 1048576 + (long)bn * 256 * Kb;

  const int scsw = (tid & 3) ^ ((tid >> 3) & 3);
  const long gOff = (long)(tid >> 2) * Kb + (long)scsw * 16;
  const int ldsb = wv * 1024;

  const int rdsw = (lk ^ ((l15 >> 1) & 3)) * 16;
  const int abase = (wr * 64 + l15) * 64;
  const int bbase = (wcn * 64 + l15) * 64;

  f32x4 acc[4][4];
#pragma unroll
  for (int i = 0; i < 4; ++i)
#pragma unroll
    for (int j = 0; j < 4; ++j) acc[i][j] = (f32x4){0.f, 0.f, 0.f, 0.f};

#define STAGEF(T, BUF)                                                        \
  {                                                                           \
    const long kb = (long)(T) * 64;                                           \
    gload16(Ab + kb + gOff, LDSU + (BUF) * 16384 + ldsb);                     \
    gload16(Bb + kb + gOff, LDSU + 65536 + (BUF) * 16384 + ldsb);             \
  }

  STAGEF(0, 0)
  STAGEF(1, 1)
  asm volatile("s_waitcnt vmcnt(2)" ::: "memory");
  SBAR;

  l2v Ac[4], Bc[4], An[4], Bn[4];
  RDFRAGS(0, Ac, Bc)

  const int NT = Kb >> 6;
  for (int t = 0; t < NT; t += 2) {
    SBAR;
    QBODY(t,     STAGEF, Ac, Bc, An, Bn)
    QBODY(t + 1, STAGEF, An, Bn, Ac, Bc)
  }
#undef STAGEF
  SBAR;

  float* scf = (float*)LDSU;           // [64][256] f32 quarter scratch (64 KiB)
  float* Cb = Out + (long)bz * 2097152;
  const float g = gptr[0];
#pragma unroll
  for (int h = 0; h < 4; ++h) {
    if (wr == h) {
#pragma unroll
      for (int i = 0; i < 4; ++i)
#pragma unroll
        for (int j = 0; j < 4; ++j) {
          const int col = wcn * 64 + j * 16 + l15;
          const int cc = col >> 2, c3 = col & 3;
#pragma unroll
          for (int r = 0; r < 4; ++r) {
            const int rl = i * 16 + lk * 4 + r;     // [0,64)
            scf[rl * 256 + ((cc ^ (rl & 15)) << 2) + c3] = acc[i][j][r];
          }
        }
    }
    SBAR;
#pragma unroll
    for (int it = 0; it < 4; ++it) {
      const int rl = it * 16 + wv;                   // [0,64)
      const int rg = bm * 256 + h * 64 + rl;         // [0,2048)
      const int c = lane;                            // f32 cell [0,64)
      fl4 a4 = *(const fl4*)&scf[rl * 256 + ((c ^ (rl & 15)) << 2)];
      const int cg = bn * 256 + c * 4;
      us4 xv = *(const us4*)&xh[((long)bz * 2048 + rg) * 1024 + cg];
      fl4 sr = *(const fl4*)&Srow[bz * 1024 + cg];
      fl4 pq4 = *(const fl4*)&pq[bz * 1024 + cg];
      fl4 qs4 = *(const fl4*)&qsum[bz * 1024 + cg];
      const float vs = Vsum[bz * 2048 + rg];
      fl4 o;
#pragma unroll
      for (int q = 0; q < 4; ++q) {
        const float tl = 1.0f / (1024.0f + sr[q] + 1e-6f * rsqrtf(pq4[q]) * qs4[q]);
        o[q] = b2f(xv[q]) + g * ((vs + a4[q]) * tl);
      }
      *(fl4*)&Cb[(long)rg * 1024 + cg] = o;
    }
    if (h < 3) SBAR;
  }
}

extern "C" void kernel_launch(void* const* d_in, const int* in_sizes, int n_in,
                              void* d_out, int out_size, void* d_ws, size_t ws_size,
                              hipStream_t stream) {
  (void)in_sizes; (void)n_in; (void)out_size;
  const float* x     = (const float*)d_in[0];
  const float* Wq    = (const float*)d_in[1];
  const float* bq    = (const float*)d_in[2];
  const float* Wk    = (const float*)d_in[3];
  const float* bk    = (const float*)d_in[4];
  const float* Wv    = (const float*)d_in[5];
  const float* bv    = (const float*)d_in[6];
  const float* gamma = (const float*)d_in[7];

  // B=16, C=2048, L=D=1024
  const long NE = 16L * 2048 * 1024;

  char* w = (char*)d_ws;
  unsigned char*  QT8 = (unsigned char*)(w);                    // [16][1024][2048] fp8
  unsigned char*  KT8 = (unsigned char*)(w + 33554432L);
  unsigned char*  V8  = (unsigned char*)(w + 67108864L);        // [32768][1024] fp8
  unsigned short* xh  = (unsigned short*)(w + 100663296L);      // bf16 residual (67MB)
  unsigned char*  x8  = (unsigned char*)(w + 167772160L);       // [32768][1024] fp8
  unsigned char*  S8  = (unsigned char*)(w + 201326592L);       // [16][1024][1024] fp8
  size_t off = 218103808L;
  unsigned char* W8   = (unsigned char*)(w + off); off += 3145728;
  char* accbase = w + off;
  float* pq     = (float*)(w + off); off += 65536;
  float* qsum   = (float*)(w + off); off += 65536;
  float* pk     = (float*)(w + off); off += 65536;
  float* Vsum   = (float*)(w + off); off += 131072;
  float* Srow   = (float*)(w + off); off += 65536;
  const size_t accbytes = (size_t)(w + off - accbase);
  float* bqkv   = (float*)(w + off); off += 12288;
  if (ws_size < off) return;

  // 0) zero atomic accumulators
  hipMemsetAsync(accbase, 0, accbytes, stream);

  // 1) casts + bias concat
  k_xcast<<<dim3((unsigned)(NE / 1024)), 256, 0, stream>>>(x, xh, x8, NE);
  k_wcast8<<<dim3(3072), 256, 0, stream>>>(Wq, Wk, Wv, W8);
  k_bias_cat<<<dim3(12), 256, 0, stream>>>(bq, bk, bv, bqkv);

  // 2) merged QKV GEMM (fp8, 16-wave): Q,K transposed fp8; V fp8 + reductions
  k_g16qkv8<<<dim3(12, 128, 1), 1024, 0, stream>>>(
      x8, W8, QT8, KT8, V8, 1024, bqkv, pq, qsum, pk, Vsum);

  // 3) S8 = fp8(rsqrt(pq).(QT8 x KT8^T).rsqrt(pk)) per batch (fused norms; 16-wave)
  k_g16s8<<<dim3(4, 4, 16), 1024, 0, stream>>>(
      QT8, KT8, S8, 2048, pq, pk, Srow);

  // 4) out = xh + gamma*(Vsum + V8 x S8^T) * tailor(Srow,pq,qsum)  (fused tailor; 16-wave)
  k_g16fin<<<dim3(4, 8, 16), 1024, 0, stream>>>(
      V8, S8, (float*)d_out, 1024, xh, Vsum, Srow, pq, qsum, gamma);
}

// Round 21
// 345.583 us; speedup vs baseline: 2.5421x; 2.5421x over previous
//
#include <hip/hip_runtime.h>
#include <cstdint>

#define DEV static __device__ __forceinline__

typedef __attribute__((ext_vector_type(4))) float f32x4;
typedef __attribute__((ext_vector_type(4))) float fl4;
typedef __attribute__((ext_vector_type(4))) unsigned short us4;
typedef __attribute__((ext_vector_type(8))) unsigned short us8;
typedef __attribute__((ext_vector_type(2))) long l2v;          // 2 x i64 (one b128)

DEV float b2f(unsigned short u) {
  union { unsigned int i; float f; } c; c.i = ((unsigned int)u) << 16; return c.f;
}
DEV unsigned short f2b(float f) {   // RNE float -> bf16 bits
  union { float f; unsigned int i; } c; c.f = f;
  unsigned int u = c.i;
  u += 0x7fffu + ((u >> 16) & 1u);
  return (unsigned short)(u >> 16);
}
DEV unsigned int f4_to_fp8x4(float a, float b, float c, float d) {  // 4 x e4m3 packed
  int r = __builtin_amdgcn_cvt_pk_fp8_f32(a, b, 0, false);
  r = __builtin_amdgcn_cvt_pk_fp8_f32(c, d, r, true);
  return (unsigned int)r;
}
DEV unsigned char f2f8(float v) {   // scalar e4m3
  return (unsigned char)__builtin_amdgcn_cvt_pk_fp8_f32(v, v, 0, false);
}

DEV void gload16(const void* g, void* l) {  // async global->LDS, 16B/lane
  __builtin_amdgcn_global_load_lds(
      (const __attribute__((address_space(1))) unsigned int*)g,
      (__attribute__((address_space(3))) unsigned int*)l, 16, 0, 0);
}

DEV float red16(float v) {  // reduce across 16 lanes sharing lk (xor low 4 bits)
  v += __shfl_xor(v, 1); v += __shfl_xor(v, 2);
  v += __shfl_xor(v, 4); v += __shfl_xor(v, 8);
  return v;
}
DEV float red4lk(float v) { // reduce across the 4 lk groups (xor bits 4,5)
  v += __shfl_xor(v, 16); v += __shfl_xor(v, 32);
  return v;
}

// ---------------- x -> bf16 (residual) + fp8 (GEMM A operand) ----------------
__global__ __launch_bounds__(256) void k_xcast(const float* __restrict__ src,
                                               unsigned short* __restrict__ dh,
                                               unsigned char* __restrict__ d8, long n) {
  long i = ((long)blockIdx.x * 256 + threadIdx.x) * 4;
  if (i >= n) return;
  fl4 v = *(const fl4*)(src + i);
  us4 o;
  o[0] = f2b(v[0]); o[1] = f2b(v[1]); o[2] = f2b(v[2]); o[3] = f2b(v[3]);
  *(us4*)(dh + i) = o;
  *(unsigned int*)(d8 + i) = f4_to_fp8x4(v[0], v[1], v[2], v[3]);
}

// ---------------- Wq|Wk|Wv -> one contiguous fp8 buffer ----------------
__global__ __launch_bounds__(256) void k_wcast8(const float* __restrict__ wq,
                                                const float* __restrict__ wk,
                                                const float* __restrict__ wv,
                                                unsigned char* __restrict__ dst) {
  const long i = ((long)blockIdx.x * 256 + threadIdx.x) * 4;   // [0, 3M)
  const int seg = (int)(i >> 20);
  const float* s = seg == 0 ? wq : (seg == 1 ? wk : wv);
  fl4 v = *(const fl4*)(s + (i & 1048575));
  *(unsigned int*)(dst + i) = f4_to_fp8x4(v[0], v[1], v[2], v[3]);
}

// ---------------- concat biases into 3072-float buffer ----------------
__global__ __launch_bounds__(256) void k_bias_cat(const float* __restrict__ bq,
                                                  const float* __restrict__ bk,
                                                  const float* __restrict__ bv,
                                                  float* __restrict__ o) {
  const int t = blockIdx.x * 256 + threadIdx.x;   // 3072
  o[t] = t < 1024 ? bq[t] : (t < 2048 ? bk[t - 1024] : bv[t - 2048]);
}

#define MFMA_FP8(A, B, C) __builtin_amdgcn_mfma_f32_16x16x32_fp8_fp8((A), (B), (C), 0, 0, 0)
#define SBAR   __builtin_amdgcn_s_barrier()

// ================= 16-WAVE fp8 QKV (R19-verbatim, measured 344 µs total) ===============
__global__ __launch_bounds__(1024, 4)
void k_g16qkv8(const unsigned char* __restrict__ A,
               const unsigned char* __restrict__ Bt,
               unsigned char* __restrict__ QT8, unsigned char* __restrict__ KT8,
               unsigned char* __restrict__ Vout8,
               int Kb,
               const float* __restrict__ bias,
               float* __restrict__ r1, float* __restrict__ r2,
               float* __restrict__ r3, float* __restrict__ r4) {
  __shared__ __align__(16) unsigned char LDSU[131072];

  const int tid = threadIdx.x;
  const int wv = tid >> 6, lane = tid & 63;
  const int wr = wv >> 2, wcn = wv & 3;          // 4 x 4 wave grid, 64x64 each
  const int l15 = lane & 15, lk = lane >> 4;

  const int nx = gridDim.x;
  const int nwg = nx * gridDim.y;
  const int lin = blockIdx.y * nx + blockIdx.x;
  const int cpx = nwg >> 3;
  const int wg = (lin & 7) * cpx + (lin >> 3);
  const int bn = wg % nx;
  const int bm = wg / nx;

  const unsigned char* Ab = A + (long)bm * 256 * Kb;
  const unsigned char* Bb = Bt + (long)bn * 256 * Kb;

  const int scsw = (tid & 3) ^ ((tid >> 3) & 3);
  const long gOff = (long)(tid >> 2) * Kb + (long)scsw * 16;   // bytes; + t*64
  const int ldsb = wv * 1024;

  const int rdsw = (lk ^ ((l15 >> 1) & 3)) * 16;
  const int abase = (wr * 64 + l15) * 64;
  const int bbase = (wcn * 64 + l15) * 64;

  f32x4 acc[4][4];
#pragma unroll
  for (int i = 0; i < 4; ++i)
#pragma unroll
    for (int j = 0; j < 4; ++j) acc[i][j] = (f32x4){0.f, 0.f, 0.f, 0.f};

#define STAGEQ(T, BUF)                                                        \
  {                                                                           \
    const long kb = (long)(T) * 64;                                           \
    gload16(Ab + kb + gOff, LDSU + (BUF) * 16384 + ldsb);                     \
    gload16(Bb + kb + gOff, LDSU + 65536 + (BUF) * 16384 + ldsb);             \
  }

  STAGEQ(0, 0)
  STAGEQ(1, 1)

  const int NT = Kb >> 6;
  for (int t = 0; t < NT; ++t) {
    if (t < NT - 1) { asm volatile("s_waitcnt vmcnt(2)" ::: "memory"); }
    else            { asm volatile("s_waitcnt vmcnt(0)" ::: "memory"); }
    if ((t & 1) == 0) SBAR;
    if (t + 2 < NT) STAGEQ(t + 2, (t + 2) & 3)

    const unsigned char* Asc = LDSU + (t & 3) * 16384;
    const unsigned char* Bsc = LDSU + 65536 + (t & 3) * 16384;
    l2v Bf[4], Af[4];
#pragma unroll
    for (int j = 0; j < 4; ++j)
      Bf[j] = *(const l2v*)&Bsc[bbase + j * 1024 + rdsw];
#pragma unroll
    for (int i = 0; i < 4; ++i)
      Af[i] = *(const l2v*)&Asc[abase + i * 1024 + rdsw];

    __builtin_amdgcn_s_setprio(1);
#pragma unroll
    for (int i = 0; i < 4; ++i)
#pragma unroll
      for (int j = 0; j < 4; ++j) {
        acc[i][j] = MFMA_FP8(Af[i][0], Bf[j][0], acc[i][j]);
        acc[i][j] = MFMA_FP8(Af[i][1], Bf[j][1], acc[i][j]);
      }
    __builtin_amdgcn_s_setprio(0);
  }
#undef STAGEQ
  SBAR;   // K-loop LDS dead -> scratch

  const int row0 = bm * 256 + wr * 64;
  const int col0 = bn * 256 + wcn * 64;

  const int seg = bn >> 2;             // 0=Q, 1=K, 2=V
  const int b = bm >> 3;               // batch
  float bvj[4];
#pragma unroll
  for (int j = 0; j < 4; ++j) bvj[j] = bias[col0 + j * 16 + l15];
  const int colL0 = col0 & 1023;
  unsigned char* sc8 = LDSU;           // [256][256B] fp8 scratch, 16B cells ^ (row&15)

  if (seg < 2) {
#pragma unroll
    for (int i = 0; i < 4; ++i)
#pragma unroll
      for (int j = 0; j < 4; ++j) {
        const int p = wcn * 64 + j * 16 + l15;
        const int m = wr * 64 + i * 16 + lk * 4;
        const unsigned int pk4 = f4_to_fp8x4(acc[i][j][0] + bvj[j], acc[i][j][1] + bvj[j],
                                             acc[i][j][2] + bvj[j], acc[i][j][3] + bvj[j]);
        *(unsigned int*)&sc8[p * 256 + (((m >> 4) ^ (p & 15)) << 4) + (m & 15)] = pk4;
      }
#pragma unroll
    for (int j = 0; j < 4; ++j) {
      const int colL = colL0 + j * 16 + l15;
      float ss = 0.f, sm = 0.f;
#pragma unroll
      for (int i = 0; i < 4; ++i)
#pragma unroll
        for (int r = 0; r < 4; ++r) {
          const float v = acc[i][j][r] + bvj[j];
          ss += v * v; sm += v;
        }
      ss = red4lk(ss);
      if (seg == 0) sm = red4lk(sm);
      if (lk == 0) {
        atomicAdd(&(seg == 0 ? r1 : r3)[(long)b * 1024 + colL], ss);
        if (seg == 0) atomicAdd(&r2[(long)b * 1024 + colL], sm);
      }
    }
    SBAR;
    unsigned char* tp = (seg == 0 ? QT8 : KT8) + (long)b * 2097152;
    const int P0 = (bn & 3) * 256;
    const int M0 = (bm & 7) * 256;
#pragma unroll
    for (int it = 0; it < 4; ++it) {
      const int p = it * 64 + (tid >> 4);
      const int c = tid & 15;
      us8 v = *(const us8*)&sc8[p * 256 + ((c ^ (p & 15)) << 4)];
      *(us8*)&tp[(long)(P0 + p) * 2048 + M0 + c * 16] = v;
    }
  } else {
#pragma unroll
    for (int i = 0; i < 4; ++i)
#pragma unroll
      for (int r = 0; r < 4; ++r) {
        const int rl = wr * 64 + i * 16 + lk * 4 + r;
        float sm = 0.f;
#pragma unroll
        for (int j = 0; j < 4; ++j) {
          const float v = acc[i][j][r] + bvj[j];
          sm += v;
          const int col = wcn * 64 + j * 16 + l15;
          sc8[rl * 256 + (((col >> 4) ^ (rl & 15)) << 4) + (col & 15)] = f2f8(v);
        }
        sm = red16(sm);
        if (l15 == 0) atomicAdd(&r4[row0 + i * 16 + lk * 4 + r], sm);
      }
    SBAR;
    const int C0 = (bn & 3) * 256;
#pragma unroll
    for (int it = 0; it < 4; ++it) {
      const int rl = it * 64 + (tid >> 4);
      const int c = tid & 15;
      us8 v = *(const us8*)&sc8[rl * 256 + ((c ^ (rl & 15)) << 4)];
      *(us8*)&Vout8[(long)(bm * 256 + rl) * 1024 + C0 + c * 16] = v;
    }
  }
}

// ================= 16-WAVE fp8 S-GEMM (+fused inverse-norm scaling) ====================
__global__ __launch_bounds__(1024, 4)
void k_g16s8(const unsigned char* __restrict__ A,
             const unsigned char* __restrict__ Bt,
             unsigned char* __restrict__ Sout,
             int Kb,
             const float* __restrict__ pq, const float* __restrict__ pk,
             float* __restrict__ Srow) {
  __shared__ __align__(16) unsigned char LDSU[131072];

  const int tid = threadIdx.x;
  const int wv = tid >> 6, lane = tid & 63;
  const int wr = wv >> 2, wcn = wv & 3;
  const int l15 = lane & 15, lk = lane >> 4;

  const int nx = gridDim.x;
  const int nwg = nx * gridDim.y;
  const int lin = blockIdx.y * nx + blockIdx.x;
  const int cpx = nwg >> 3;
  const int wg = (lin & 7) * cpx + (lin >> 3);
  const int bn = wg % nx;
  const int bm = wg / nx;
  const int bz = blockIdx.z;

  const unsigned char* Ab = A + (long)bz * 2097152 + (long)bm * 256 * Kb;
  const unsigned char* Bb = Bt + (long)bz * 2097152 + (long)bn * 256 * Kb;

  const int scsw = (tid & 3) ^ ((tid >> 3) & 3);
  const long gOff = (long)(tid >> 2) * Kb + (long)scsw * 16;
  const int ldsb = wv * 1024;

  const int rdsw = (lk ^ ((l15 >> 1) & 3)) * 16;
  const int abase = (wr * 64 + l15) * 64;
  const int bbase = (wcn * 64 + l15) * 64;

  f32x4 acc[4][4];
#pragma unroll
  for (int i = 0; i < 4; ++i)
#pragma unroll
    for (int j = 0; j < 4; ++j) acc[i][j] = (f32x4){0.f, 0.f, 0.f, 0.f};

#define STAGES(T, BUF)                                                        \
  {                                                                           \
    const long kb = (long)(T) * 64;                                           \
    gload16(Ab + kb + gOff, LDSU + (BUF) * 16384 + ldsb);                     \
    gload16(Bb + kb + gOff, LDSU + 65536 + (BUF) * 16384 + ldsb);             \
  }

  STAGES(0, 0)
  STAGES(1, 1)

  const int NT = Kb >> 6;
  for (int t = 0; t < NT; ++t) {
    if (t < NT - 1) { asm volatile("s_waitcnt vmcnt(2)" ::: "memory"); }
    else            { asm volatile("s_waitcnt vmcnt(0)" ::: "memory"); }
    if ((t & 1) == 0) SBAR;
    if (t + 2 < NT) STAGES(t + 2, (t + 2) & 3)

    const unsigned char* Asc = LDSU + (t & 3) * 16384;
    const unsigned char* Bsc = LDSU + 65536 + (t & 3) * 16384;
    l2v Bf[4], Af[4];
#pragma unroll
    for (int j = 0; j < 4; ++j)
      Bf[j] = *(const l2v*)&Bsc[bbase + j * 1024 + rdsw];
#pragma unroll
    for (int i = 0; i < 4; ++i)
      Af[i] = *(const l2v*)&Asc[abase + i * 1024 + rdsw];

    __builtin_amdgcn_s_setprio(1);
#pragma unroll
    for (int i = 0; i < 4; ++i)
#pragma unroll
      for (int j = 0; j < 4; ++j) {
        acc[i][j] = MFMA_FP8(Af[i][0], Bf[j][0], acc[i][j]);
        acc[i][j] = MFMA_FP8(Af[i][1], Bf[j][1], acc[i][j]);
      }
    __builtin_amdgcn_s_setprio(0);
  }
#undef STAGES
  SBAR;

  const int row0 = bm * 256 + wr * 64;
  const int col0 = bn * 256 + wcn * 64;
  unsigned char* sc8 = LDSU;

  float ivk[4];
#pragma unroll
  for (int j = 0; j < 4; ++j) ivk[j] = rsqrtf(pk[bz * 1024 + col0 + j * 16 + l15]);
#pragma unroll
  for (int i = 0; i < 4; ++i)
#pragma unroll
    for (int r = 0; r < 4; ++r) {
      const int rl = wr * 64 + i * 16 + lk * 4 + r;
      const float ivq = rsqrtf(pq[bz * 1024 + row0 + i * 16 + lk * 4 + r]);
      float sm = 0.f;
#pragma unroll
      for (int j = 0; j < 4; ++j) {
        const float v = acc[i][j][r] * ivq * ivk[j];
        sm += v;
        const int col = wcn * 64 + j * 16 + l15;
        sc8[rl * 256 + (((col >> 4) ^ (rl & 15)) << 4) + (col & 15)] = f2f8(v);
      }
      sm = red16(sm);
      if (l15 == 0) atomicAdd(&Srow[(long)bz * 1024 + row0 + i * 16 + lk * 4 + r], sm);
    }
  SBAR;
  unsigned char* Cb = Sout + (long)bz * 1048576;
#pragma unroll
  for (int it = 0; it < 4; ++it) {
    const int rl = it * 64 + (tid >> 4);
    const int c = tid & 15;
    us8 v = *(const us8*)&sc8[rl * 256 + ((c ^ (rl & 15)) << 4)];
    *(us8*)&Cb[(long)(bm * 256 + rl) * 1024 + bn * 256 + c * 16] = v;
  }
}

// ================= 16-WAVE fp8 final GEMM (+fused tailor) ==============================
__global__ __launch_bounds__(1024, 4)
void k_g16fin(const unsigned char* __restrict__ A,
              const unsigned char* __restrict__ Bt,
              float* __restrict__ Out,
              int Kb,
              const unsigned short* __restrict__ xh,
              const float* __restrict__ Vsum,
              const float* __restrict__ Srow,
              const float* __restrict__ pq,
              const float* __restrict__ qsum,
              const float* __restrict__ gptr) {
  __shared__ __align__(16) unsigned char LDSU[131072];

  const int tid = threadIdx.x;
  const int wv = tid >> 6, lane = tid & 63;
  const int wr = wv >> 2, wcn = wv & 3;
  const int l15 = lane & 15, lk = lane >> 4;

  const int nx = gridDim.x;
  const int nwg = nx * gridDim.y;
  const int lin = blockIdx.y * nx + blockIdx.x;
  const int cpx = nwg >> 3;
  const int wg = (lin & 7) * cpx + (lin >> 3);
  const int bn = wg % nx;
  const int bm = wg / nx;
  const int bz = blockIdx.z;

  const unsigned char* Ab = A + (long)bz * 2097152 + (long)bm * 256 * Kb;
  const unsigned char* Bb = Bt + (long)bz * 1048576 + (long)bn * 256 * Kb;

  const int scsw = (tid & 3) ^ ((tid >> 3) & 3);
  const long gOff = (long)(tid >> 2) * Kb + (long)scsw * 16;
  const int ldsb = wv * 1024;

  const int rdsw = (lk ^ ((l15 >> 1) & 3)) * 16;
  const int abase = (wr * 64 + l15) * 64;
  const int bbase = (wcn * 64 + l15) * 64;

  f32x4 acc[4][4];
#pragma unroll
  for (int i = 0; i < 4; ++i)
#pragma unroll
    for (int j = 0; j < 4; ++j) acc[i][j] = (f32x4){0.f, 0.f, 0.f, 0.f};

#define STAGEF(T, BUF)                                                        \
  {                                                                           \
    const long kb = (long)(T) * 64;                                           \
    gload16(Ab + kb + gOff, LDSU + (BUF) * 16384 + ldsb);                     \
    gload16(Bb + kb + gOff, LDSU + 65536 + (BUF) * 16384 + ldsb);             \
  }

  STAGEF(0, 0)
  STAGEF(1, 1)

  const int NT = Kb >> 6;
  for (int t = 0; t < NT; ++t) {
    if (t < NT - 1) { asm volatile("s_waitcnt vmcnt(2)" ::: "memory"); }
    else            { asm volatile("s_waitcnt vmcnt(0)" ::: "memory"); }
    if ((t & 1) == 0) SBAR;
    if (t + 2 < NT) STAGEF(t + 2, (t + 2) & 3)

    const unsigned char* Asc = LDSU + (t & 3) * 16384;
    const unsigned char* Bsc = LDSU + 65536 + (t & 3) * 16384;
    l2v Bf[4], Af[4];
#pragma unroll
    for (int j = 0; j < 4; ++j)
      Bf[j] = *(const l2v*)&Bsc[bbase + j * 1024 + rdsw];
#pragma unroll
    for (int i = 0; i < 4; ++i)
      Af[i] = *(const l2v*)&Asc[abase + i * 1024 + rdsw];

    __builtin_amdgcn_s_setprio(1);
#pragma unroll
    for (int i = 0; i < 4; ++i)
#pragma unroll
      for (int j = 0; j < 4; ++j) {
        acc[i][j] = MFMA_FP8(Af[i][0], Bf[j][0], acc[i][j]);
        acc[i][j] = MFMA_FP8(Af[i][1], Bf[j][1], acc[i][j]);
      }
    __builtin_amdgcn_s_setprio(0);
  }
#undef STAGEF
  SBAR;

  float* scf = (float*)LDSU;           // [64][256] f32 quarter scratch (64 KiB)
  float* Cb = Out + (long)bz * 2097152;
  const float g = gptr[0];
#pragma unroll
  for (int h = 0; h < 4; ++h) {
    if (wr == h) {
#pragma unroll
      for (int i = 0; i < 4; ++i)
#pragma unroll
        for (int j = 0; j < 4; ++j) {
          const int col = wcn * 64 + j * 16 + l15;
          const int cc = col >> 2, c3 = col & 3;
#pragma unroll
          for (int r = 0; r < 4; ++r) {
            const int rl = i * 16 + lk * 4 + r;     // [0,64)
            scf[rl * 256 + ((cc ^ (rl & 15)) << 2) + c3] = acc[i][j][r];
          }
        }
    }
    SBAR;
#pragma unroll
    for (int it = 0; it < 4; ++it) {
      const int rl = it * 16 + wv;                   // [0,64)
      const int rg = bm * 256 + h * 64 + rl;         // [0,2048)
      const int c = lane;                            // f32 cell [0,64)
      fl4 a4 = *(const fl4*)&scf[rl * 256 + ((c ^ (rl & 15)) << 2)];
      const int cg = bn * 256 + c * 4;
      us4 xv = *(const us4*)&xh[((long)bz * 2048 + rg) * 1024 + cg];
      fl4 sr = *(const fl4*)&Srow[bz * 1024 + cg];
      fl4 pq4 = *(const fl4*)&pq[bz * 1024 + cg];
      fl4 qs4 = *(const fl4*)&qsum[bz * 1024 + cg];
      const float vs = Vsum[bz * 2048 + rg];
      fl4 o;
#pragma unroll
      for (int q = 0; q < 4; ++q) {
        const float tl = 1.0f / (1024.0f + sr[q] + 1e-6f * rsqrtf(pq4[q]) * qs4[q]);
        o[q] = b2f(xv[q]) + g * ((vs + a4[q]) * tl);
      }
      *(fl4*)&Cb[(long)rg * 1024 + cg] = o;
    }
    if (h < 3) SBAR;
  }
}

extern "C" void kernel_launch(void* const* d_in, const int* in_sizes, int n_in,
                              void* d_out, int out_size, void* d_ws, size_t ws_size,
                              hipStream_t stream) {
  (void)in_sizes; (void)n_in; (void)out_size;
  const float* x     = (const float*)d_in[0];
  const float* Wq    = (const float*)d_in[1];
  const float* bq    = (const float*)d_in[2];
  const float* Wk    = (const float*)d_in[3];
  const float* bk    = (const float*)d_in[4];
  const float* Wv    = (const float*)d_in[5];
  const float* bv    = (const float*)d_in[6];
  const float* gamma = (const float*)d_in[7];

  // B=16, C=2048, L=D=1024
  const long NE = 16L * 2048 * 1024;

  char* w = (char*)d_ws;
  unsigned char*  QT8 = (unsigned char*)(w);                    // [16][1024][2048] fp8
  unsigned char*  KT8 = (unsigned char*)(w + 33554432L);
  unsigned char*  V8  = (unsigned char*)(w + 67108864L);        // [32768][1024] fp8
  unsigned short* xh  = (unsigned short*)(w + 100663296L);      // bf16 residual (67MB)
  unsigned char*  x8  = (unsigned char*)(w + 167772160L);       // [32768][1024] fp8
  unsigned char*  S8  = (unsigned char*)(w + 201326592L);       // [16][1024][1024] fp8
  size_t off = 218103808L;
  unsigned char* W8   = (unsigned char*)(w + off); off += 3145728;
  char* accbase = w + off;
  float* pq     = (float*)(w + off); off += 65536;
  float* qsum   = (float*)(w + off); off += 65536;
  float* pk     = (float*)(w + off); off += 65536;
  float* Vsum   = (float*)(w + off); off += 131072;
  float* Srow   = (float*)(w + off); off += 65536;
  const size_t accbytes = (size_t)(w + off - accbase);
  float* bqkv   = (float*)(w + off); off += 12288;
  if (ws_size < off) return;

  // 0) zero atomic accumulators
  hipMemsetAsync(accbase, 0, accbytes, stream);

  // 1) casts + bias concat
  k_xcast<<<dim3((unsigned)(NE / 1024)), 256, 0, stream>>>(x, xh, x8, NE);
  k_wcast8<<<dim3(3072), 256, 0, stream>>>(Wq, Wk, Wv, W8);
  k_bias_cat<<<dim3(12), 256, 0, stream>>>(bq, bk, bv, bqkv);

  // 2) merged QKV GEMM (fp8, 16-wave): Q,K transposed fp8; V fp8 + reductions
  k_g16qkv8<<<dim3(12, 128, 1), 1024, 0, stream>>>(
      x8, W8, QT8, KT8, V8, 1024, bqkv, pq, qsum, pk, Vsum);

  // 3) S8 = fp8(rsqrt(pq).(QT8 x KT8^T).rsqrt(pk)) per batch (fused norms; 16-wave)
  k_g16s8<<<dim3(4, 4, 16), 1024, 0, stream>>>(
      QT8, KT8, S8, 2048, pq, pk, Srow);

  // 4) out = xh + gamma*(Vsum + V8 x S8^T) * tailor(Srow,pq,qsum)  (fused tailor; 16-wave)
  k_g16fin<<<dim3(4, 8, 16), 1024, 0, stream>>>(
      V8, S8, (float*)d_out, 1024, xh, Vsum, Srow, pq, qsum, gamma);
}

// Round 22
// 331.907 us; speedup vs baseline: 2.6468x; 1.0412x over previous
//
#include <hip/hip_runtime.h>
#include <cstdint>

#define DEV static __device__ __forceinline__

typedef __attribute__((ext_vector_type(4))) float f32x4;
typedef __attribute__((ext_vector_type(4))) float fl4;
typedef __attribute__((ext_vector_type(4))) unsigned short us4;
typedef __attribute__((ext_vector_type(8))) unsigned short us8;
typedef __attribute__((ext_vector_type(2))) long l2v;          // 2 x i64 (one b128)

DEV float b2f(unsigned short u) {
  union { unsigned int i; float f; } c; c.i = ((unsigned int)u) << 16; return c.f;
}
DEV unsigned short f2b(float f) {   // RNE float -> bf16 bits
  union { float f; unsigned int i; } c; c.f = f;
  unsigned int u = c.i;
  u += 0x7fffu + ((u >> 16) & 1u);
  return (unsigned short)(u >> 16);
}
DEV unsigned int f4_to_fp8x4(float a, float b, float c, float d) {  // 4 x e4m3 packed
  int r = __builtin_amdgcn_cvt_pk_fp8_f32(a, b, 0, false);
  r = __builtin_amdgcn_cvt_pk_fp8_f32(c, d, r, true);
  return (unsigned int)r;
}
DEV unsigned char f2f8(float v) {   // scalar e4m3
  return (unsigned char)__builtin_amdgcn_cvt_pk_fp8_f32(v, v, 0, false);
}

DEV void gload16(const void* g, void* l) {  // async global->LDS, 16B/lane
  __builtin_amdgcn_global_load_lds(
      (const __attribute__((address_space(1))) unsigned int*)g,
      (__attribute__((address_space(3))) unsigned int*)l, 16, 0, 0);
}

DEV float red16(float v) {  // reduce across 16 lanes sharing lk (xor low 4 bits)
  v += __shfl_xor(v, 1); v += __shfl_xor(v, 2);
  v += __shfl_xor(v, 4); v += __shfl_xor(v, 8);
  return v;
}
DEV float red4lk(float v) { // reduce across the 4 lk groups (xor bits 4,5)
  v += __shfl_xor(v, 16); v += __shfl_xor(v, 32);
  return v;
}

// ---------------- x -> bf16 (residual) + fp8 (GEMM A operand) ----------------
__global__ __launch_bounds__(256) void k_xcast(const float* __restrict__ src,
                                               unsigned short* __restrict__ dh,
                                               unsigned char* __restrict__ d8, long n) {
  long i = ((long)blockIdx.x * 256 + threadIdx.x) * 4;
  if (i >= n) return;
  fl4 v = *(const fl4*)(src + i);
  us4 o;
  o[0] = f2b(v[0]); o[1] = f2b(v[1]); o[2] = f2b(v[2]); o[3] = f2b(v[3]);
  *(us4*)(dh + i) = o;
  *(unsigned int*)(d8 + i) = f4_to_fp8x4(v[0], v[1], v[2], v[3]);
}

// ---------------- Wq|Wk|Wv -> one contiguous fp8 buffer ----------------
__global__ __launch_bounds__(256) void k_wcast8(const float* __restrict__ wq,
                                                const float* __restrict__ wk,
                                                const float* __restrict__ wv,
                                                unsigned char* __restrict__ dst) {
  const long i = ((long)blockIdx.x * 256 + threadIdx.x) * 4;   // [0, 3M)
  const int seg = (int)(i >> 20);
  const float* s = seg == 0 ? wq : (seg == 1 ? wk : wv);
  fl4 v = *(const fl4*)(s + (i & 1048575));
  *(unsigned int*)(dst + i) = f4_to_fp8x4(v[0], v[1], v[2], v[3]);
}

// ---------------- concat biases into 3072-float buffer ----------------
__global__ __launch_bounds__(256) void k_bias_cat(const float* __restrict__ bq,
                                                  const float* __restrict__ bk,
                                                  const float* __restrict__ bv,
                                                  float* __restrict__ o) {
  const int t = blockIdx.x * 256 + threadIdx.x;   // 3072
  o[t] = t < 1024 ? bq[t] : (t < 2048 ? bk[t - 1024] : bv[t - 2048]);
}

#define MFMA_FP8(A, B, C) __builtin_amdgcn_mfma_f32_16x16x32_fp8_fp8((A), (B), (C), 0, 0, 0)
#define SBAR   __builtin_amdgcn_s_barrier()

// ================= 8-WAVE fp8 QKV, 128x256 tile, 3 LDS bufs = 72 KiB -> 2 blocks/CU ====
// Two co-resident blocks have INDEPENDENT barrier domains: when one block's waves drain
// at its s_barrier/vmcnt, the other block's waves keep the SIMDs fed (cross-block overlap
// needs no source support — m114). Schedule per tile t: vmcnt(3) [drains stage(t), keeps
// stage(t+1) in flight; 0 only at last tile] -> SBAR -> issue stage(t+2) into buf (t+2)%3
// [= (t-1)%3, last read at tile t-1, all reads precede every wave's tile-t barrier -> safe]
// -> read frags buf t%3 -> MFMA. acc stays 4x4 (no R20 register blowup; lb(512,4)).
__global__ __launch_bounds__(512, 4)
void k_g8qkv8(const unsigned char* __restrict__ A,
              const unsigned char* __restrict__ Bt,
              unsigned char* __restrict__ QT8, unsigned char* __restrict__ KT8,
              unsigned char* __restrict__ Vout8,
              int Kb,
              const float* __restrict__ bias,
              float* __restrict__ r1, float* __restrict__ r2,
              float* __restrict__ r3, float* __restrict__ r4) {
  __shared__ __align__(16) unsigned char LDSU[73728];  // A 3x8K @0, B 3x16K @24576

  const int tid = threadIdx.x;
  const int wv = tid >> 6, lane = tid & 63;
  const int wr = wv >> 2, wcn = wv & 3;          // 2 x 4 wave grid, 64x64 each
  const int l15 = lane & 15, lk = lane >> 4;

  const int nx = gridDim.x;                      // 12
  const int nwg = nx * gridDim.y;                // 3072, %8 == 0
  const int lin = blockIdx.y * nx + blockIdx.x;
  const int cpx = nwg >> 3;
  const int wg = (lin & 7) * cpx + (lin >> 3);
  const int bn = wg % nx;
  const int bm = wg / nx;                        // [0,256): 128-row tiles

  const unsigned char* Ab = A + (long)bm * 128 * Kb;
  const unsigned char* Bb = Bt + (long)bn * 256 * Kb;

  // staging: row = tid>>2 in [0,128), phys chunk tid&3, pre-swz global chunk.
  const int scsw = (tid & 3) ^ ((tid >> 3) & 3);
  const long gOff = (long)(tid >> 2) * Kb + (long)scsw * 16;   // bytes; + t*64
  const int ldsb = wv * 1024;                                   // 8 waves * 1KB = 8KB/gload

  const int rdsw = (lk ^ ((l15 >> 1) & 3)) * 16;
  const int abase = (wr * 64 + l15) * 64;    // A rows [0,128)
  const int bbase = (wcn * 64 + l15) * 64;   // B rows [0,256)

  f32x4 acc[4][4];
#pragma unroll
  for (int i = 0; i < 4; ++i)
#pragma unroll
    for (int j = 0; j < 4; ++j) acc[i][j] = (f32x4){0.f, 0.f, 0.f, 0.f};

#define STAGEQ(T, BUF)                                                              \
  {                                                                                 \
    const long kb = (long)(T) * 64;                                                 \
    gload16(Ab + kb + gOff,             LDSU + (BUF) * 8192 + ldsb);                \
    gload16(Bb + kb + gOff,             LDSU + 24576 + (BUF) * 16384 + ldsb);       \
    gload16(Bb + kb + gOff + 128L * Kb, LDSU + 24576 + (BUF) * 16384 + 8192 + ldsb);\
  }

  STAGEQ(0, 0)
  STAGEQ(1, 1)

  const int NT = Kb >> 6;   // 16
  for (int t = 0; t < NT; ++t) {
    if (t < NT - 1) { asm volatile("s_waitcnt vmcnt(3)" ::: "memory"); }
    else            { asm volatile("s_waitcnt vmcnt(0)" ::: "memory"); }
    SBAR;
    if (t + 2 < NT) { STAGEQ(t + 2, (t + 2) % 3) }

    const unsigned char* Asc = LDSU + (t % 3) * 8192;
    const unsigned char* Bsc = LDSU + 24576 + (t % 3) * 16384;
    l2v Bf[4], Af[4];
#pragma unroll
    for (int j = 0; j < 4; ++j)
      Bf[j] = *(const l2v*)&Bsc[bbase + j * 1024 + rdsw];
#pragma unroll
    for (int i = 0; i < 4; ++i)
      Af[i] = *(const l2v*)&Asc[abase + i * 1024 + rdsw];

    __builtin_amdgcn_s_setprio(1);
#pragma unroll
    for (int i = 0; i < 4; ++i)
#pragma unroll
      for (int j = 0; j < 4; ++j) {
        acc[i][j] = MFMA_FP8(Af[i][0], Bf[j][0], acc[i][j]);
        acc[i][j] = MFMA_FP8(Af[i][1], Bf[j][1], acc[i][j]);
      }
    __builtin_amdgcn_s_setprio(0);
  }
#undef STAGEQ
  SBAR;   // K-loop LDS dead -> scratch

  const int col0 = bn * 256 + wcn * 64;
  const int seg = bn >> 2;             // 0=Q, 1=K, 2=V
  const int b = bm >> 4;               // batch (2048 rows / 128-row tiles)
  float bvj[4];
#pragma unroll
  for (int j = 0; j < 4; ++j) bvj[j] = bias[col0 + j * 16 + l15];
  const int colL0 = col0 & 1023;
  unsigned char* sc8 = LDSU;

  if (seg < 2) {
    // transposed fp8 scratch: [256 p][128 B], 16B cells, cell ^= p&7
#pragma unroll
    for (int i = 0; i < 4; ++i)
#pragma unroll
      for (int j = 0; j < 4; ++j) {
        const int p = wcn * 64 + j * 16 + l15;        // [0,256)
        const int m = wr * 64 + i * 16 + lk * 4;      // [0,128), aligned 4
        const unsigned int pk4 = f4_to_fp8x4(acc[i][j][0] + bvj[j], acc[i][j][1] + bvj[j],
                                             acc[i][j][2] + bvj[j], acc[i][j][3] + bvj[j]);
        *(unsigned int*)&sc8[p * 128 + (((m >> 4) ^ (p & 7)) << 4) + (m & 15)] = pk4;
      }
    // col reductions over this block's 128 rows (both wr-waves of a wcn add)
#pragma unroll
    for (int j = 0; j < 4; ++j) {
      const int colL = colL0 + j * 16 + l15;
      float ss = 0.f, sm = 0.f;
#pragma unroll
      for (int i = 0; i < 4; ++i)
#pragma unroll
        for (int r = 0; r < 4; ++r) {
          const float v = acc[i][j][r] + bvj[j];
          ss += v * v; sm += v;
        }
      ss = red4lk(ss);
      if (seg == 0) sm = red4lk(sm);
      if (lk == 0) {
        atomicAdd(&(seg == 0 ? r1 : r3)[(long)b * 1024 + colL], ss);
        if (seg == 0) atomicAdd(&r2[(long)b * 1024 + colL], sm);
      }
    }
    SBAR;
    unsigned char* tp = (seg == 0 ? QT8 : KT8) + (long)b * 2097152;
    const int P0 = (bn & 3) * 256;
    const int M0 = (bm & 15) * 128;
#pragma unroll
    for (int it = 0; it < 4; ++it) {
      const int p = it * 64 + (tid >> 3);            // [0,256)
      const int c = tid & 7;
      us8 v = *(const us8*)&sc8[p * 128 + ((c ^ (p & 7)) << 4)];
      *(us8*)&tp[(long)(P0 + p) * 2048 + M0 + c * 16] = v;
    }
  } else {
    // V: fp8 normal layout [128 rl][256 B] + fp32 row sums
#pragma unroll
    for (int i = 0; i < 4; ++i)
#pragma unroll
      for (int r = 0; r < 4; ++r) {
        const int rl = wr * 64 + i * 16 + lk * 4 + r;   // [0,128)
        float sm = 0.f;
#pragma unroll
        for (int j = 0; j < 4; ++j) {
          const float v = acc[i][j][r] + bvj[j];
          sm += v;
          const int col = wcn * 64 + j * 16 + l15;
          sc8[rl * 256 + (((col >> 4) ^ (rl & 15)) << 4) + (col & 15)] = f2f8(v);
        }
        sm = red16(sm);
        if (l15 == 0) atomicAdd(&r4[bm * 128 + rl], sm);
      }
    SBAR;
    const int C0 = (bn & 3) * 256;
#pragma unroll
    for (int it = 0; it < 4; ++it) {
      const int rl = it * 32 + (tid >> 4);            // [0,128)
      const int c = tid & 15;
      us8 v = *(const us8*)&sc8[rl * 256 + ((c ^ (rl & 15)) << 4)];
      *(us8*)&Vout8[(long)(bm * 128 + rl) * 1024 + C0 + c * 16] = v;
    }
  }
}

// ================= 16-WAVE fp8 S-GEMM (R19-verbatim control) ===========================
__global__ __launch_bounds__(1024, 4)
void k_g16s8(const unsigned char* __restrict__ A,
             const unsigned char* __restrict__ Bt,
             unsigned char* __restrict__ Sout,
             int Kb,
             const float* __restrict__ pq, const float* __restrict__ pk,
             float* __restrict__ Srow) {
  __shared__ __align__(16) unsigned char LDSU[131072];

  const int tid = threadIdx.x;
  const int wv = tid >> 6, lane = tid & 63;
  const int wr = wv >> 2, wcn = wv & 3;
  const int l15 = lane & 15, lk = lane >> 4;

  const int nx = gridDim.x;
  const int nwg = nx * gridDim.y;
  const int lin = blockIdx.y * nx + blockIdx.x;
  const int cpx = nwg >> 3;
  const int wg = (lin & 7) * cpx + (lin >> 3);
  const int bn = wg % nx;
  const int bm = wg / nx;
  const int bz = blockIdx.z;

  const unsigned char* Ab = A + (long)bz * 2097152 + (long)bm * 256 * Kb;
  const unsigned char* Bb = Bt + (long)bz * 2097152 + (long)bn * 256 * Kb;

  const int scsw = (tid & 3) ^ ((tid >> 3) & 3);
  const long gOff = (long)(tid >> 2) * Kb + (long)scsw * 16;
  const int ldsb = wv * 1024;

  const int rdsw = (lk ^ ((l15 >> 1) & 3)) * 16;
  const int abase = (wr * 64 + l15) * 64;
  const int bbase = (wcn * 64 + l15) * 64;

  f32x4 acc[4][4];
#pragma unroll
  for (int i = 0; i < 4; ++i)
#pragma unroll
    for (int j = 0; j < 4; ++j) acc[i][j] = (f32x4){0.f, 0.f, 0.f, 0.f};

#define STAGES(T, BUF)                                                        \
  {                                                                           \
    const long kb = (long)(T) * 64;                                           \
    gload16(Ab + kb + gOff, LDSU + (BUF) * 16384 + ldsb);                     \
    gload16(Bb + kb + gOff, LDSU + 65536 + (BUF) * 16384 + ldsb);             \
  }

  STAGES(0, 0)
  STAGES(1, 1)

  const int NT = Kb >> 6;
  for (int t = 0; t < NT; ++t) {
    if (t < NT - 1) { asm volatile("s_waitcnt vmcnt(2)" ::: "memory"); }
    else            { asm volatile("s_waitcnt vmcnt(0)" ::: "memory"); }
    if ((t & 1) == 0) SBAR;
    if (t + 2 < NT) STAGES(t + 2, (t + 2) & 3)

    const unsigned char* Asc = LDSU + (t & 3) * 16384;
    const unsigned char* Bsc = LDSU + 65536 + (t & 3) * 16384;
    l2v Bf[4], Af[4];
#pragma unroll
    for (int j = 0; j < 4; ++j)
      Bf[j] = *(const l2v*)&Bsc[bbase + j * 1024 + rdsw];
#pragma unroll
    for (int i = 0; i < 4; ++i)
      Af[i] = *(const l2v*)&Asc[abase + i * 1024 + rdsw];

    __builtin_amdgcn_s_setprio(1);
#pragma unroll
    for (int i = 0; i < 4; ++i)
#pragma unroll
      for (int j = 0; j < 4; ++j) {
        acc[i][j] = MFMA_FP8(Af[i][0], Bf[j][0], acc[i][j]);
        acc[i][j] = MFMA_FP8(Af[i][1], Bf[j][1], acc[i][j]);
      }
    __builtin_amdgcn_s_setprio(0);
  }
#undef STAGES
  SBAR;

  const int row0 = bm * 256 + wr * 64;
  const int col0 = bn * 256 + wcn * 64;
  unsigned char* sc8 = LDSU;

  float ivk[4];
#pragma unroll
  for (int j = 0; j < 4; ++j) ivk[j] = rsqrtf(pk[bz * 1024 + col0 + j * 16 + l15]);
#pragma unroll
  for (int i = 0; i < 4; ++i)
#pragma unroll
    for (int r = 0; r < 4; ++r) {
      const int rl = wr * 64 + i * 16 + lk * 4 + r;
      const float ivq = rsqrtf(pq[bz * 1024 + row0 + i * 16 + lk * 4 + r]);
      float sm = 0.f;
#pragma unroll
      for (int j = 0; j < 4; ++j) {
        const float v = acc[i][j][r] * ivq * ivk[j];
        sm += v;
        const int col = wcn * 64 + j * 16 + l15;
        sc8[rl * 256 + (((col >> 4) ^ (rl & 15)) << 4) + (col & 15)] = f2f8(v);
      }
      sm = red16(sm);
      if (l15 == 0) atomicAdd(&Srow[(long)bz * 1024 + row0 + i * 16 + lk * 4 + r], sm);
    }
  SBAR;
  unsigned char* Cb = Sout + (long)bz * 1048576;
#pragma unroll
  for (int it = 0; it < 4; ++it) {
    const int rl = it * 64 + (tid >> 4);
    const int c = tid & 15;
    us8 v = *(const us8*)&sc8[rl * 256 + ((c ^ (rl & 15)) << 4)];
    *(us8*)&Cb[(long)(bm * 256 + rl) * 1024 + bn * 256 + c * 16] = v;
  }
}

// ================= 16-WAVE fp8 final GEMM (R19-verbatim control) =======================
__global__ __launch_bounds__(1024, 4)
void k_g16fin(const unsigned char* __restrict__ A,
              const unsigned char* __restrict__ Bt,
              float* __restrict__ Out,
              int Kb,
              const unsigned short* __restrict__ xh,
              const float* __restrict__ Vsum,
              const float* __restrict__ Srow,
              const float* __restrict__ pq,
              const float* __restrict__ qsum,
              const float* __restrict__ gptr) {
  __shared__ __align__(16) unsigned char LDSU[131072];

  const int tid = threadIdx.x;
  const int wv = tid >> 6, lane = tid & 63;
  const int wr = wv >> 2, wcn = wv & 3;
  const int l15 = lane & 15, lk = lane >> 4;

  const int nx = gridDim.x;
  const int nwg = nx * gridDim.y;
  const int lin = blockIdx.y * nx + blockIdx.x;
  const int cpx = nwg >> 3;
  const int wg = (lin & 7) * cpx + (lin >> 3);
  const int bn = wg % nx;
  const int bm = wg / nx;
  const int bz = blockIdx.z;

  const unsigned char* Ab = A + (long)bz * 2097152 + (long)bm * 256 * Kb;
  const unsigned char* Bb = Bt + (long)bz * 1048576 + (long)bn * 256 * Kb;

  const int scsw = (tid & 3) ^ ((tid >> 3) & 3);
  const long gOff = (long)(tid >> 2) * Kb + (long)scsw * 16;
  const int ldsb = wv * 1024;

  const int rdsw = (lk ^ ((l15 >> 1) & 3)) * 16;
  const int abase = (wr * 64 + l15) * 64;
  const int bbase = (wcn * 64 + l15) * 64;

  f32x4 acc[4][4];
#pragma unroll
  for (int i = 0; i < 4; ++i)
#pragma unroll
    for (int j = 0; j < 4; ++j) acc[i][j] = (f32x4){0.f, 0.f, 0.f, 0.f};

#define STAGEF(T, BUF)                                                        \
  {                                                                           \
    const long kb = (long)(T) * 64;                                           \
    gload16(Ab + kb + gOff, LDSU + (BUF) * 16384 + ldsb);                     \
    gload16(Bb + kb + gOff, LDSU + 65536 + (BUF) * 16384 + ldsb);             \
  }

  STAGEF(0, 0)
  STAGEF(1, 1)

  const int NT = Kb >> 6;
  for (int t = 0; t < NT; ++t) {
    if (t < NT - 1) { asm volatile("s_waitcnt vmcnt(2)" ::: "memory"); }
    else            { asm volatile("s_waitcnt vmcnt(0)" ::: "memory"); }
    if ((t & 1) == 0) SBAR;
    if (t + 2 < NT) STAGEF(t + 2, (t + 2) & 3)

    const unsigned char* Asc = LDSU + (t & 3) * 16384;
    const unsigned char* Bsc = LDSU + 65536 + (t & 3) * 16384;
    l2v Bf[4], Af[4];
#pragma unroll
    for (int j = 0; j < 4; ++j)
      Bf[j] = *(const l2v*)&Bsc[bbase + j * 1024 + rdsw];
#pragma unroll
    for (int i = 0; i < 4; ++i)
      Af[i] = *(const l2v*)&Asc[abase + i * 1024 + rdsw];

    __builtin_amdgcn_s_setprio(1);
#pragma unroll
    for (int i = 0; i < 4; ++i)
#pragma unroll
      for (int j = 0; j < 4; ++j) {
        acc[i][j] = MFMA_FP8(Af[i][0], Bf[j][0], acc[i][j]);
        acc[i][j] = MFMA_FP8(Af[i][1], Bf[j][1], acc[i][j]);
      }
    __builtin_amdgcn_s_setprio(0);
  }
#undef STAGEF
  SBAR;

  float* scf = (float*)LDSU;           // [64][256] f32 quarter scratch (64 KiB)
  float* Cb = Out + (long)bz * 2097152;
  const float g = gptr[0];
#pragma unroll
  for (int h = 0; h < 4; ++h) {
    if (wr == h) {
#pragma unroll
      for (int i = 0; i < 4; ++i)
#pragma unroll
        for (int j = 0; j < 4; ++j) {
          const int col = wcn * 64 + j * 16 + l15;
          const int cc = col >> 2, c3 = col & 3;
#pragma unroll
          for (int r = 0; r < 4; ++r) {
            const int rl = i * 16 + lk * 4 + r;     // [0,64)
            scf[rl * 256 + ((cc ^ (rl & 15)) << 2) + c3] = acc[i][j][r];
          }
        }
    }
    SBAR;
#pragma unroll
    for (int it = 0; it < 4; ++it) {
      const int rl = it * 16 + wv;                   // [0,64)
      const int rg = bm * 256 + h * 64 + rl;         // [0,2048)
      const int c = lane;                            // f32 cell [0,64)
      fl4 a4 = *(const fl4*)&scf[rl * 256 + ((c ^ (rl & 15)) << 2)];
      const int cg = bn * 256 + c * 4;
      us4 xv = *(const us4*)&xh[((long)bz * 2048 + rg) * 1024 + cg];
      fl4 sr = *(const fl4*)&Srow[bz * 1024 + cg];
      fl4 pq4 = *(const fl4*)&pq[bz * 1024 + cg];
      fl4 qs4 = *(const fl4*)&qsum[bz * 1024 + cg];
      const float vs = Vsum[bz * 2048 + rg];
      fl4 o;
#pragma unroll
      for (int q = 0; q < 4; ++q) {
        const float tl = 1.0f / (1024.0f + sr[q] + 1e-6f * rsqrtf(pq4[q]) * qs4[q]);
        o[q] = b2f(xv[q]) + g * ((vs + a4[q]) * tl);
      }
      *(fl4*)&Cb[(long)rg * 1024 + cg] = o;
    }
    if (h < 3) SBAR;
  }
}

extern "C" void kernel_launch(void* const* d_in, const int* in_sizes, int n_in,
                              void* d_out, int out_size, void* d_ws, size_t ws_size,
                              hipStream_t stream) {
  (void)in_sizes; (void)n_in; (void)out_size;
  const float* x     = (const float*)d_in[0];
  const float* Wq    = (const float*)d_in[1];
  const float* bq    = (const float*)d_in[2];
  const float* Wk    = (const float*)d_in[3];
  const float* bk    = (const float*)d_in[4];
  const float* Wv    = (const float*)d_in[5];
  const float* bv    = (const float*)d_in[6];
  const float* gamma = (const float*)d_in[7];

  // B=16, C=2048, L=D=1024
  const long NE = 16L * 2048 * 1024;

  char* w = (char*)d_ws;
  unsigned char*  QT8 = (unsigned char*)(w);                    // [16][1024][2048] fp8
  unsigned char*  KT8 = (unsigned char*)(w + 33554432L);
  unsigned char*  V8  = (unsigned char*)(w + 67108864L);        // [32768][1024] fp8
  unsigned short* xh  = (unsigned short*)(w + 100663296L);      // bf16 residual (67MB)
  unsigned char*  x8  = (unsigned char*)(w + 167772160L);       // [32768][1024] fp8
  unsigned char*  S8  = (unsigned char*)(w + 201326592L);       // [16][1024][1024] fp8
  size_t off = 218103808L;
  unsigned char* W8   = (unsigned char*)(w + off); off += 3145728;
  char* accbase = w + off;
  float* pq     = (float*)(w + off); off += 65536;
  float* qsum   = (float*)(w + off); off += 65536;
  float* pk     = (float*)(w + off); off += 65536;
  float* Vsum   = (float*)(w + off); off += 131072;
  float* Srow   = (float*)(w + off); off += 65536;
  const size_t accbytes = (size_t)(w + off - accbase);
  float* bqkv   = (float*)(w + off); off += 12288;
  if (ws_size < off) return;

  // 0) zero atomic accumulators
  hipMemsetAsync(accbase, 0, accbytes, stream);

  // 1) casts + bias concat
  k_xcast<<<dim3((unsigned)(NE / 1024)), 256, 0, stream>>>(x, xh, x8, NE);
  k_wcast8<<<dim3(3072), 256, 0, stream>>>(Wq, Wk, Wv, W8);
  k_bias_cat<<<dim3(12), 256, 0, stream>>>(bq, bk, bv, bqkv);

  // 2) merged QKV GEMM (fp8, 8-wave 128x256, 2 blocks/CU): Q,K transposed; V + reductions
  k_g8qkv8<<<dim3(12, 256, 1), 512, 0, stream>>>(
      x8, W8, QT8, KT8, V8, 1024, bqkv, pq, qsum, pk, Vsum);

  // 3) S8 = fp8(rsqrt(pq).(QT8 x KT8^T).rsqrt(pk)) per batch (fused norms; 16-wave)
  k_g16s8<<<dim3(4, 4, 16), 1024, 0, stream>>>(
      QT8, KT8, S8, 2048, pq, pk, Srow);

  // 4) out = xh + gamma*(Vsum + V8 x S8^T) * tailor(Srow,pq,qsum)  (fused tailor; 16-wave)
  k_g16fin<<<dim3(4, 8, 16), 1024, 0, stream>>>(
      V8, S8, (float*)d_out, 1024, xh, Vsum, Srow, pq, qsum, gamma);
}